// Round 11
// baseline (285.937 us; speedup 1.0000x reference)
//
#include <hip/hip_runtime.h>

// OctVolSynth: element-wise over 256^3 volume.
//   scaling = lut[label]; v = scaling*texture; v = (v==0) ? 1 : v;
//   out0 = parenchyma * v;  out1 = (label != 0) ? 1.0f : 0.0f
//
// Session: fifteen structural variants (16B/4B width, asm-forced MLP depth,
// persistence, nt / sc0-sc1 store scope, block geometry, per-thread
// amortization, LDS-LUT deletion) all pin demand-side service at 3.2-3.8
// TB/s with FETCH/WRITE bit-constant; R15 (base, 90us) has 81% occupancy,
// zero LDS, zero conflicts, 7.4% VALU -- every CU resource idle. Gap to the
// 6.3 TB/s copy anchor is 1.7x and the only unisolated variable is the
// concurrent stream MIX (3R+2W+gather vs copy's 1R+1W).
//
// R16 isolates it: two sequential dispatches. A = volume (3R+1W), B = mask
// (1R+1W, exactly copy-shaped). Costs +64MiB (labels read twice); wins if
// simpler mixes lift the rate >20%. Decisive either way: B at ~6 TB/s =>
// mix is real; B at ~3.7 => even copy-shape is capped here => roofline
// declaration next round is airtight.

#define N_ELEMS (256 * 256 * 256)
#define BLOCK 1024

__global__ __launch_bounds__(BLOCK) void octvolsynth_r16_vol(
    const int* __restrict__ labels,
    const float* __restrict__ parenchyma,
    const float* __restrict__ texture,
    const float* __restrict__ lut,
    float* __restrict__ out)
{
    const int i = blockIdx.x * BLOCK + threadIdx.x;

    const int   l = labels[i];
    const float p = parenchyma[i];
    const float x = texture[i];
    const float s = lut[l];          // tiny gather, L1-hot

    float v = s * x;
    v = (v == 0.0f) ? 1.0f : v;

    out[i] = p * v;
}

__global__ __launch_bounds__(BLOCK) void octvolsynth_r16_mask(
    const int* __restrict__ labels,
    float* __restrict__ outm)
{
    const int i = blockIdx.x * BLOCK + threadIdx.x;
    outm[i] = (labels[i] != 0) ? 1.0f : 0.0f;
}

extern "C" void kernel_launch(void* const* d_in, const int* in_sizes, int n_in,
                              void* d_out, int out_size, void* d_ws, size_t ws_size,
                              hipStream_t stream) {
    const int*   labels     = (const int*)d_in[0];
    const float* parenchyma = (const float*)d_in[1];
    const float* texture    = (const float*)d_in[2];
    const float* lut        = (const float*)d_in[3];
    float* out = (float*)d_out;

    const int grid = N_ELEMS / BLOCK;   // 16384 blocks, no tail
    octvolsynth_r16_vol <<<grid, BLOCK, 0, stream>>>(labels, parenchyma, texture, lut, out);
    octvolsynth_r16_mask<<<grid, BLOCK, 0, stream>>>(labels, out + N_ELEMS);
}

// Round 12
// 271.668 us; speedup vs baseline: 1.0525x; 1.0525x over previous
//
#include <hip/hip_runtime.h>

// OctVolSynth: element-wise over 256^3 volume.
//   scaling = lut[label]; v = scaling*texture; v = (v==0) ? 1 : v;
//   out0 = parenchyma * v;  out1 = (label != 0) ? 1.0f : 0.0f
//
// Session: 16 structural variants. Only width ever moved throughput:
// 16B/lane = 3.24 TB/s (99us), 4B/lane = 3.77 TB/s (88-91us, R10/R15 base).
// Null axes, traffic counters bit-constant throughout: asm-forced MLP depth
// (R7/R12 -- deeper queues INFLATE latency, R12 held 2x outstanding bytes
// and lost), persistence (R11), store scope nt/sc0sc1 (R8/R13), geometry,
// per-thread amortization (R14), LDS-LUT deletion (R15, occ 81%, conflicts
// 0, dur null), kernel split (R16: vol 3R+1W still 2.44 TB/s read-side;
// mask 1R+1W ~10 TB/s L3-served -- fabric can go 3x faster for simple
// shapes; split total regressed, merged base stands).
//
// R17 completes the width curve at its last untested point: 8B/lane
// (dwordx2 -- the common CDNA streaming optimum). Single variable vs R15.
// Predict: peak-at-8B -> 82-86us, ~4.1 TB/s; 4B-optimum -> 92-97us and the
// width curve is complete => declare structural roofline next round.

#define N_ELEMS (256 * 256 * 256)
#define BLOCK 1024

typedef float vfloat2 __attribute__((ext_vector_type(2)));
typedef int   vint2   __attribute__((ext_vector_type(2)));

__global__ __launch_bounds__(BLOCK) void octvolsynth_r17(
    const int* __restrict__ labels,
    const float* __restrict__ parenchyma,
    const float* __restrict__ texture,
    const float* __restrict__ lut,
    float* __restrict__ out)
{
    const int i2 = blockIdx.x * BLOCK + threadIdx.x;   // int2/float2 index

    const vint2   l2 = ((const vint2*)  labels)    [i2];
    const vfloat2 p2 = ((const vfloat2*)parenchyma)[i2];
    const vfloat2 x2 = ((const vfloat2*)texture)   [i2];

    const float s0 = lut[l2.x];        // tiny gather, L1-hot
    const float s1 = lut[l2.y];

    float v0 = s0 * x2.x;
    float v1 = s1 * x2.y;
    v0 = (v0 == 0.0f) ? 1.0f : v0;
    v1 = (v1 == 0.0f) ? 1.0f : v1;

    vfloat2 fv, mv;
    fv.x = p2.x * v0;
    fv.y = p2.y * v1;
    mv.x = (l2.x != 0) ? 1.0f : 0.0f;
    mv.y = (l2.y != 0) ? 1.0f : 0.0f;

    ((vfloat2*)out)[i2]                  = fv;
    ((vfloat2*)(out + N_ELEMS))[i2]      = mv;
}

extern "C" void kernel_launch(void* const* d_in, const int* in_sizes, int n_in,
                              void* d_out, int out_size, void* d_ws, size_t ws_size,
                              hipStream_t stream) {
    const int*   labels     = (const int*)d_in[0];
    const float* parenchyma = (const float*)d_in[1];
    const float* texture    = (const float*)d_in[2];
    const float* lut        = (const float*)d_in[3];
    float* out = (float*)d_out;

    const int grid = (N_ELEMS / 2) / BLOCK;   // 8192 blocks, no tail
    octvolsynth_r17<<<grid, BLOCK, 0, stream>>>(labels, parenchyma, texture, lut, out);
}